// Round 18
// baseline (114.871 us; speedup 1.0000x reference)
//
#include <hip/hip_runtime.h>
#include <hip/hip_bf16.h>

typedef __attribute__((ext_vector_type(8))) short bf16x8;
typedef __attribute__((ext_vector_type(4))) float f32x4;

#define MFMA16(a,b,c) __builtin_amdgcn_mfma_f32_16x16x32_bf16((a),(b),(c),0,0,0)
#define GLDS16(g, l) __builtin_amdgcn_global_load_lds((const __attribute__((address_space(1))) void*)(g), (__attribute__((address_space(3))) void*)(l), 16, 0, 0)

static constexpr int S_ = 2048, E_ = 1024, H_ = 16;
static constexpr float QS = 0.125f * 1.44269504f;   // scale * log2(e)

__device__ __forceinline__ unsigned pk2(float a, float b) {
  __hip_bfloat16 ba = __float2bfloat16(a), bb = __float2bfloat16(b);
  return (unsigned)*(unsigned short*)&ba | ((unsigned)*(unsigned short*)&bb << 16);
}
__device__ __forceinline__ float ubf(unsigned short u) {
  return __uint_as_float((unsigned)u << 16);
}

// ---------------- fused prep ----------------
__global__ __launch_bounds__(256) void prep_k(const float* __restrict__ x, const float* __restrict__ rel,
                                              const float* __restrict__ Wq, const float* __restrict__ Wk,
                                              const float* __restrict__ Wv, const float* __restrict__ Wo,
                                              const float* __restrict__ bq, const float* __restrict__ bk,
                                              const float* __restrict__ bv,
                                              __hip_bfloat16* __restrict__ xb, __hip_bfloat16* __restrict__ relb,
                                              __hip_bfloat16* __restrict__ wqkvT, __hip_bfloat16* __restrict__ woT,
                                              float* __restrict__ bqkv, float* __restrict__ cost,
                                              float* __restrict__ sint) {
  int blk = blockIdx.x, tid = threadIdx.x;
  if (blk < 1024) {
    __shared__ float tile[64][65];
    int wsel = blk >> 8, sub = blk & 255;
    const float* W = wsel == 0 ? Wq : wsel == 1 ? Wk : wsel == 2 ? Wv : Wo;
    __hip_bfloat16* WT = wsel < 3 ? wqkvT + (size_t)wsel * E_ * E_ : woT;
    int bx = sub & 15, by = sub >> 4;
    for (int i = tid; i < 4096; i += 256) {
      int ki = i >> 6, ni = i & 63;
      tile[ki][ni] = W[(size_t)(by*64 + ki) * E_ + bx*64 + ni];
    }
    __syncthreads();
    for (int i = tid; i < 4096; i += 256) {
      int ni = i >> 6, ki = i & 63;
      WT[(size_t)(bx*64 + ni) * E_ + by*64 + ki] = __float2bfloat16(tile[ki][ni]);
    }
  } else if (blk < 3072) {
    int i = (blk - 1024) * 256 + tid;
    float4 v = reinterpret_cast<const float4*>(x)[i];
    xb[4*i+0] = __float2bfloat16(v.x);
    xb[4*i+1] = __float2bfloat16(v.y);
    xb[4*i+2] = __float2bfloat16(v.z);
    xb[4*i+3] = __float2bfloat16(v.w);
  } else if (blk < 3328) {
    int i = (blk - 3072) * 256 + tid;
    if (i < 65520) {
      float4 v = reinterpret_cast<const float4*>(rel)[i];
      relb[4*i+0] = __float2bfloat16(v.x * 8.f);
      relb[4*i+1] = __float2bfloat16(v.y * 8.f);
      relb[4*i+2] = __float2bfloat16(v.z * 8.f);
      relb[4*i+3] = __float2bfloat16(v.w * 8.f);
    }
  } else if (blk < 3584) {
    int idx = (blk - 3328) * 256 + tid;
    int f = idx & 31, s = idx >> 5;
    float inv = powf(10000.f, -(float)f * (1.f/32.f));
    float a = (float)s * inv;
    cost[idx] = cosf(a);
    sint[idx] = sinf(a);
  } else {
    int i = (blk - 3584) * 256 + tid;
    if (i < 3072) bqkv[i] = i < 1024 ? bq[i] : (i < 2048 ? bk[i-1024] : bv[i-2048]);
  }
}

// ---------------- GEMM core ----------------
// MODE 0: fused QKV epilogue (rope for q/k -> [H][S][64]; V -> TRANSPOSED [H][64][S])
// MODE 1: f32 out + bias
// MODE 2: A = combine(opart0, opart1; ml) in reg-staged A path; f32 out + bias
template<int BM, int MODE>
__global__ __launch_bounds__(256) void gemm_k(const __hip_bfloat16* __restrict__ A,
                                              const __hip_bfloat16* __restrict__ BT,
                                              const float* __restrict__ bias,
                                              const float* __restrict__ cost,
                                              const float* __restrict__ sint,
                                              __hip_bfloat16* __restrict__ qhh,
                                              __hip_bfloat16* __restrict__ khh,
                                              __hip_bfloat16* __restrict__ vt,
                                              float* __restrict__ outf,
                                              const float2* __restrict__ ml2,
                                              int K) {
  constexpr int MI = BM/32;
  __shared__ __hip_bfloat16 As[2][BM*64];
  __shared__ __hip_bfloat16 Bs[2][128*64];
  int tid = threadIdx.x, lane = tid & 63, w = tid >> 6;
  int rowq = lane & 15, hi = lane >> 4, ksel = hi << 3;
  int wr = (w >> 1) * (BM/2), wc = (w & 1) * 64;
  int m0 = blockIdx.y * BM, n0 = blockIdx.x * 128;
  int l3 = lane >> 3, l7 = lane & 7;
  f32x4 acc[MI][4] = {};

  auto stage = [&](int k0, int buf) {
    const char* Bp = (const char*)BT + ((size_t)(n0 + w*32) * K + k0) * 2;
    char* Bd = (char*)&Bs[buf][w*32*64];
    for (int i = 0; i < 4; ++i)
      GLDS16(Bp + (size_t)(i*8 + l3)*(K*2) + l7*16, Bd + i*1024);
    if constexpr (MODE != 2) {
      const char* Ap = (const char*)A + ((size_t)(m0 + w*(BM/4)) * K + k0) * 2;
      char* Ad = (char*)&As[buf][w*(BM/4)*64];
      for (int i = 0; i < MI; ++i)
        GLDS16(Ap + (size_t)(i*8 + l3)*(K*2) + l7*16, Ad + i*1024);
    } else {
      int hh = k0 >> 6;
      #pragma unroll
      for (int i = 0; i < MI; ++i) {
        int row = m0 + w*(BM/4) + i*8 + l3;
        const int* o0 = (const int*)((const unsigned short*)A + (size_t)row*E_ + k0 + l7*8);
        int4 u0 = *(const int4*)o0;
        int4 u1 = *(const int4*)(o0 + (size_t)S_*E_/2);
        float2 a0 = ml2[(size_t)row*H_ + hh];
        float2 a1 = ml2[((size_t)S_ + row)*H_ + hh];
        float M = fmaxf(a0.x, a1.x);
        float w0 = exp2f(a0.x - M), w1 = exp2f(a1.x - M);
        float dinv = 1.0f / (w0*a0.y + w1*a1.y);
        w0 *= dinv; w1 *= dinv;
        auto comb2 = [&](int x0, int x1) -> unsigned {
          float lo = w0*ubf((unsigned short)(x0 & 0xffff)) + w1*ubf((unsigned short)(x1 & 0xffff));
          float hiv = w0*ubf((unsigned short)((unsigned)x0 >> 16)) + w1*ubf((unsigned short)((unsigned)x1 >> 16));
          return pk2(lo, hiv);
        };
        int res[4];
        res[0] = (int)comb2(u0.x, u1.x);
        res[1] = (int)comb2(u0.y, u1.y);
        res[2] = (int)comb2(u0.z, u1.z);
        res[3] = (int)comb2(u0.w, u1.w);
        *(int4*)&As[buf][(w*(BM/4) + i*8 + l3)*64 + l7*8] = *(int4*)res;
      }
    }
  };

  stage(0, 0);
  __syncthreads();
  int buf = 0;
  int nk = K >> 6;
  for (int t = 0; t < nk; ++t) {
    if (t + 1 < nk) stage((t+1)*64, buf^1);
    for (int kk = 0; kk < 64; kk += 32) {
      bf16x8 a[MI], b[4];
      for (int i = 0; i < MI; ++i) a[i] = *(const bf16x8*)&As[buf][(wr + i*16 + rowq)*64 + kk + ksel];
      for (int j = 0; j < 4; ++j)  b[j] = *(const bf16x8*)&Bs[buf][(wc + j*16 + rowq)*64 + kk + ksel];
      for (int i = 0; i < MI; ++i)
        for (int j = 0; j < 4; ++j)
          acc[i][j] = MFMA16(a[i], b[j], acc[i][j]);
    }
    __syncthreads();
    buf ^= 1;
  }

  if constexpr (MODE == 0) {
    int matsel = n0 >> 10, ncol = n0 & 1023;
    float bcol[4];
    for (int j = 0; j < 4; ++j) bcol[j] = bias[n0 + wc + j*16 + rowq];
    if (matsel < 2) {
      __hip_bfloat16* dst = matsel ? khh : qhh;
      float qs = matsel ? 1.0f : QS;
      for (int i = 0; i < MI; ++i)
        for (int rg = 0; rg < 4; ++rg) {
          int s = m0 + wr + i*16 + hi*4 + rg;
          for (int j = 0; j < 2; ++j) {
            int colp = ncol + wc + j*16 + rowq;
            int hh = colp >> 6, f = colp & 31;
            float c = cost[s*32 + f], sn = sint[s*32 + f];
            float v1 = acc[i][j][rg]   + bcol[j];
            float v2 = acc[i][j+2][rg] + bcol[j+2];
            dst[((size_t)hh*S_ + s)*64 + f]      = __float2bfloat16((v1*c - v2*sn) * qs);
            dst[((size_t)hh*S_ + s)*64 + f + 32] = __float2bfloat16((v2*c + v1*sn) * qs);
          }
        }
    } else {
      for (int i = 0; i < MI; ++i)
        for (int j = 0; j < 4; ++j) {
          int colp = ncol + wc + j*16 + rowq;
          int hh = colp >> 6, d = colp & 63;
          int s0b = m0 + wr + i*16 + hi*4;
          __hip_bfloat16 tmp[4];
          for (int rg = 0; rg < 4; ++rg)
            tmp[rg] = __float2bfloat16(acc[i][j][rg] + bcol[j]);
          *(ushort4*)(vt + ((size_t)hh*64 + d)*S_ + s0b) = *(ushort4*)tmp;
        }
    }
  } else {
    for (int i = 0; i < MI; ++i)
      for (int rg = 0; rg < 4; ++rg) {
        int row = m0 + wr + i*16 + hi*4 + rg;
        for (int j = 0; j < 4; ++j) {
          int col = n0 + wc + j*16 + rowq;
          outf[(size_t)row*E_ + col] = acc[i][j][rg] + bias[col];
        }
      }
  }
}

// ---------------- attention: 4-wave, 2-way split-K, f32 W window, counted-vmcnt barrier ----
__global__ __launch_bounds__(256,2) void attn_k(const __hip_bfloat16* __restrict__ qh,
                                                const __hip_bfloat16* __restrict__ kh,
                                                const __hip_bfloat16* __restrict__ vt,
                                                const __hip_bfloat16* __restrict__ relb,
                                                __hip_bfloat16* __restrict__ opart,
                                                float2* __restrict__ ml) {
  int h = blockIdx.x & 15, p = blockIdx.x >> 4;
  int tid = threadIdx.x, lane = tid & 63, w = tid >> 6;   // w in [0,4)
  int rowq = lane & 15, hi = lane >> 4, ksel = hi << 3;
  int l3 = lane >> 3, l7 = lane & 7;
  int swz = (l7*16) ^ (l3 << 4);
  __shared__ __hip_bfloat16 Ks[2][4096];      // [64][64] linear, XOR-swizzled content
  __shared__ __hip_bfloat16 Vs[2][4096];      // [d][key] linear, XOR-swizzled content
  __shared__ float Wf[4][16*82];              // f32 W window: 16 rows x 328B
  __shared__ char  Psb[4][4096];              // P bf16: 16 rows x 256B, 16B-XOR
  float* wrow = &Wf[w][rowq*82];
  char* pp = Psb[w] + rowq*256;
  int sw8 = (rowq & 7) << 4;
  int pcol0 = ((hi*16)      ^ ((rowq & 7) << 4)) >> 1;
  int pcol1 = ((64 + hi*16) ^ ((rowq & 7) << 4)) >> 1;
  int c0 = hi*4 + 15 - rowq;

  for (int ph = 0; ph < 2; ++ph) {
    int qb = ph ? 31 - p : p;
    int T = qb + 1;
    int t0 = ph ? (T + 1) >> 1 : 0;
    int t1 = ph ? T : (T + 1) >> 1;
    int i0w = qb*64 + w*16;

    const __hip_bfloat16* qrow = qh + ((size_t)h*S_ + i0w + rowq)*64 + ksel;
    bf16x8 q0 = *(const bf16x8*)(qrow);
    bf16x8 q1 = *(const bf16x8*)(qrow + 32);
    f32x4 o[4] = {};
    float m = -1e30f, l = 0.f;

    auto stage = [&](int t, int buf) {
      int j0 = t * 64;
      const char* kp = (const char*)(kh + ((size_t)h*S_ + j0 + w*16)*64);
      const char* vp = (const char*)(vt + ((size_t)(h*64 + w*16))*S_ + j0);
      char* kd = (char*)&Ks[buf][w*16*64];
      char* vd = (char*)&Vs[buf][w*16*64];
      for (int i = 0; i < 2; ++i) {
        GLDS16(kp + (size_t)(i*8 + l3)*128  + swz, kd + i*1024);
        GLDS16(vp + (size_t)(i*8 + l3)*4096 + swz, vd + i*1024);
      }
    };
    auto ldrel = [&](int t, bf16x8* rr) {
      const __hip_bfloat16* rp = relb + (size_t)(t*64 - i0w + 2032 + rowq)*64 + ksel;
      #pragma unroll
      for (int nf = 0; nf < 5; ++nf) {
        rr[nf*2]   = *(const bf16x8*)(rp + nf*1024);
        rr[nf*2+1] = *(const bf16x8*)(rp + nf*1024 + 32);
      }
    };

    if (t0 < t1) {
      bf16x8 rc[10];
      ldrel(t0, rc);
      stage(t0, 0);
      __syncthreads();
      int buf = 0;
      for (int t = t0; t < t1; ++t) {
        bool more = (t + 1 < t1);
        if (more) stage(t+1, buf^1);

        f32x4 sa[4] = {};
        f32x4 wt[5] = {};
        __builtin_amdgcn_s_setprio(1);
        for (int kk = 0; kk < 2; ++kk) {
          bf16x8 qf = kk ? q1 : q0;
          int pc = kk ? pcol1 : pcol0;
          for (int nf = 0; nf < 4; ++nf) {
            bf16x8 kf = *(const bf16x8*)&Ks[buf][(nf*16 + rowq)*64 + pc];
            sa[nf] = MFMA16(kf, qf, sa[nf]);          // D[key][q]
          }
          for (int nf = 0; nf < 5; ++nf)
            wt[nf] = MFMA16(rc[nf*2+kk], qf, wt[nf]); // D[relrow][q]
        }
        __builtin_amdgcn_s_setprio(0);

        // store W window (f32, un-swizzled 328B-stride rows -> ~4-way max)
        #pragma unroll
        for (int nf = 0; nf < 5; ++nf) {
          *(float2*)(wrow + nf*16 + hi*4)     = make_float2(wt[nf][0], wt[nf][1]);
          *(float2*)(wrow + nf*16 + hi*4 + 2) = make_float2(wt[nf][2], wt[nf][3]);
        }

        // single-buffer rel prefetch: rc's MFMA readers are done, reload in place
        if (more) ldrel(t+1, rc);

        // gather bias + softmax (lane-local, q=rowq); mask only the diagonal tile
        float sv[4][4];
        #pragma unroll
        for (int rg = 0; rg < 4; ++rg) {
          int cc = c0 + rg;
          #pragma unroll
          for (int nf = 0; nf < 4; ++nf)
            sv[nf][rg] = sa[nf][rg] + wrow[nf*16 + cc];
        }
        float tm = -1e30f;
        bool diag = (t == qb);
        int lim = w*16 + rowq;
        #pragma unroll
        for (int nf = 0; nf < 4; ++nf)
          #pragma unroll
          for (int rg = 0; rg < 4; ++rg) {
            int kl = nf*16 + hi*4 + rg;
            if (diag && kl > lim) sv[nf][rg] = -1e30f;
            tm = fmaxf(tm, sv[nf][rg]);
          }
        tm = fmaxf(tm, __shfl_xor(tm, 16));
        tm = fmaxf(tm, __shfl_xor(tm, 32));

        // defer-max: skip rescale when tile max is within 8 of running max (wave-uniform)
        bool defer = __all(tm <= m + 8.0f);
        float al = 1.0f;
        if (!defer) {
          float mnew = fmaxf(m, tm);
          al = exp2f(m - mnew);
          m = mnew;
        }
        float ls = 0.f;
        float pe[4][4];
        #pragma unroll
        for (int nf = 0; nf < 4; ++nf)
          #pragma unroll
          for (int rg = 0; rg < 4; ++rg) {
            float e = exp2f(sv[nf][rg] - m);
            pe[nf][rg] = e;
            ls += e;
          }
        l = l * al + ls;
        #pragma unroll
        for (int nf = 0; nf < 4; ++nf) {
          uint2 u = { pk2(pe[nf][0], pe[nf][1]), pk2(pe[nf][2], pe[nf][3]) };
          *(uint2*)(pp + ((nf*32 + hi*8) ^ sw8)) = u;
        }
        if (!defer) {
          float alq[4];
          #pragma unroll
          for (int rg = 0; rg < 4; ++rg) alq[rg] = __shfl(al, hi*4 + rg, 16);
          #pragma unroll
          for (int df = 0; df < 4; ++df)
            #pragma unroll
            for (int rg = 0; rg < 4; ++rg) o[df][rg] *= alq[rg];
        }

        // PV
        __builtin_amdgcn_s_setprio(1);
        for (int kk = 0; kk < 2; ++kk) {
          bf16x8 a = *(const bf16x8*)(pp + ((kk*64 + hi*16) ^ sw8));
          int pc = kk ? pcol1 : pcol0;
          for (int df = 0; df < 4; ++df) {
            bf16x8 b = *(const bf16x8*)&Vs[buf][(df*16 + rowq)*64 + pc];
            o[df] = MFMA16(a, b, o[df]);
          }
        }
        __builtin_amdgcn_s_setprio(0);

        // counted-vmcnt barrier (T4-lite)
        __builtin_amdgcn_sched_barrier(0);
        asm volatile("s_waitcnt vmcnt(10)" ::: "memory");
        __builtin_amdgcn_s_barrier();
        __builtin_amdgcn_sched_barrier(0);
        buf ^= 1;
      }
    }

    // phase epilogue: partial o (unnormalized), m, l for slot ph
    float lt = l;
    lt += __shfl_xor(lt, 16);
    lt += __shfl_xor(lt, 32);
    if (lane < 16) ml[((size_t)ph*S_ + i0w + rowq)*H_ + h] = make_float2(m, lt);
    #pragma unroll
    for (int df = 0; df < 4; ++df)
      #pragma unroll
      for (int rg = 0; rg < 4; ++rg)
        opart[(size_t)ph*S_*E_ + (size_t)(i0w + hi*4 + rg)*E_ + h*64 + df*16 + rowq] =
            __float2bfloat16(o[df][rg]);
    __syncthreads();
  }
}

// ---------------- launcher ----------------
extern "C" void kernel_launch(void* const* d_in, const int* in_sizes, int n_in,
                              void* d_out, int out_size, void* d_ws, size_t ws_size,
                              hipStream_t stream) {
  const float* x   = (const float*)d_in[0];
  const float* Wq  = (const float*)d_in[2];
  const float* bq  = (const float*)d_in[3];
  const float* Wk  = (const float*)d_in[4];
  const float* bk  = (const float*)d_in[5];
  const float* Wv  = (const float*)d_in[6];
  const float* bv  = (const float*)d_in[7];
  const float* Wo  = (const float*)d_in[8];
  const float* bo  = (const float*)d_in[9];
  const float* rel = (const float*)d_in[10];
  float* out = (float*)d_out;

  char* ws = (char*)d_ws;
  size_t off = 0;
  auto alloc = [&](size_t bytes) -> void* {
    void* p = ws + off;
    off = (off + bytes + 255) & ~(size_t)255;
    return p;
  };
  // ---- region dead during attn (aliased by opart, 8 MB) ----
  __hip_bfloat16* xb    = (__hip_bfloat16*)alloc((size_t)S_*E_*2);       // 4 MB
  __hip_bfloat16* wqkvT = (__hip_bfloat16*)alloc((size_t)3*E_*E_*2);     // 6 MB
  float* cost = (float*)alloc((size_t)S_*32*4);
  float* sint = (float*)alloc((size_t)S_*32*4);
  float* bqkv = (float*)alloc((size_t)3072*4);
  if (off < (size_t)16*1024*1024) off = (size_t)16*1024*1024;
  // ---- live during attn + out-proj ----
  __hip_bfloat16* woT   = (__hip_bfloat16*)alloc((size_t)E_*E_*2);
  __hip_bfloat16* relb  = (__hip_bfloat16*)alloc((size_t)4095*64*2);
  __hip_bfloat16* qhh  = (__hip_bfloat16*)alloc((size_t)S_*E_*2);
  __hip_bfloat16* khh  = (__hip_bfloat16*)alloc((size_t)S_*E_*2);
  __hip_bfloat16* vth  = (__hip_bfloat16*)alloc((size_t)S_*E_*2);
  float2* ml = (float2*)alloc((size_t)2*S_*H_*8);

  __hip_bfloat16* opart = (__hip_bfloat16*)ws;   // 8 MB over the attn-dead prefix

  prep_k<<<3596, 256, 0, stream>>>(x, rel, Wq, Wk, Wv, Wo, bq, bk, bv,
                                   xb, relb, wqkvT, woT, bqkv, cost, sint);

  // fused QKV projection + rope + V-transpose (BM=64: 768 blocks = 3/CU exact)
  gemm_k<64,0><<<dim3(24,32), 256, 0, stream>>>(xb, wqkvT, bqkv, cost, sint,
                                                qhh, khh, vth, nullptr, nullptr, E_);

  attn_k<<<512, 256, 0, stream>>>(qhh, khh, vth, relb, opart, ml);

  // out-projection: BM=32 -> 512 blocks = 2/CU, combine fused into A-staging
  gemm_k<32,2><<<dim3(8,64), 256, 0, stream>>>(opart, woT, bo, nullptr, nullptr,
                                               nullptr, nullptr, nullptr, out, ml, E_);
}

// Round 19
// 112.369 us; speedup vs baseline: 1.0223x; 1.0223x over previous
//
#include <hip/hip_runtime.h>
#include <hip/hip_bf16.h>

typedef __attribute__((ext_vector_type(8))) short bf16x8;
typedef __attribute__((ext_vector_type(4))) float f32x4;

#define MFMA16(a,b,c) __builtin_amdgcn_mfma_f32_16x16x32_bf16((a),(b),(c),0,0,0)
#define GLDS16(g, l) __builtin_amdgcn_global_load_lds((const __attribute__((address_space(1))) void*)(g), (__attribute__((address_space(3))) void*)(l), 16, 0, 0)

static constexpr int S_ = 2048, E_ = 1024, H_ = 16;
static constexpr float QS = 0.125f * 1.44269504f;   // scale * log2(e)

__device__ __forceinline__ unsigned pk2(float a, float b) {
  __hip_bfloat16 ba = __float2bfloat16(a), bb = __float2bfloat16(b);
  return (unsigned)*(unsigned short*)&ba | ((unsigned)*(unsigned short*)&bb << 16);
}
__device__ __forceinline__ float ubf(unsigned short u) {
  return __uint_as_float((unsigned)u << 16);
}

// ---------------- fused prep ----------------
__global__ __launch_bounds__(256) void prep_k(const float* __restrict__ x, const float* __restrict__ rel,
                                              const float* __restrict__ Wq, const float* __restrict__ Wk,
                                              const float* __restrict__ Wv, const float* __restrict__ Wo,
                                              const float* __restrict__ bq, const float* __restrict__ bk,
                                              const float* __restrict__ bv,
                                              __hip_bfloat16* __restrict__ xb, __hip_bfloat16* __restrict__ relb,
                                              __hip_bfloat16* __restrict__ wqkvT, __hip_bfloat16* __restrict__ woT,
                                              float* __restrict__ bqkv, float* __restrict__ cost,
                                              float* __restrict__ sint) {
  int blk = blockIdx.x, tid = threadIdx.x;
  if (blk < 1024) {
    __shared__ float tile[64][65];
    int wsel = blk >> 8, sub = blk & 255;
    const float* W = wsel == 0 ? Wq : wsel == 1 ? Wk : wsel == 2 ? Wv : Wo;
    __hip_bfloat16* WT = wsel < 3 ? wqkvT + (size_t)wsel * E_ * E_ : woT;
    int bx = sub & 15, by = sub >> 4;
    for (int i = tid; i < 4096; i += 256) {
      int ki = i >> 6, ni = i & 63;
      tile[ki][ni] = W[(size_t)(by*64 + ki) * E_ + bx*64 + ni];
    }
    __syncthreads();
    for (int i = tid; i < 4096; i += 256) {
      int ni = i >> 6, ki = i & 63;
      WT[(size_t)(bx*64 + ni) * E_ + by*64 + ki] = __float2bfloat16(tile[ki][ni]);
    }
  } else if (blk < 3072) {
    int i = (blk - 1024) * 256 + tid;
    float4 v = reinterpret_cast<const float4*>(x)[i];
    xb[4*i+0] = __float2bfloat16(v.x);
    xb[4*i+1] = __float2bfloat16(v.y);
    xb[4*i+2] = __float2bfloat16(v.z);
    xb[4*i+3] = __float2bfloat16(v.w);
  } else if (blk < 3328) {
    int i = (blk - 3072) * 256 + tid;
    if (i < 65520) {
      float4 v = reinterpret_cast<const float4*>(rel)[i];
      relb[4*i+0] = __float2bfloat16(v.x * 8.f);
      relb[4*i+1] = __float2bfloat16(v.y * 8.f);
      relb[4*i+2] = __float2bfloat16(v.z * 8.f);
      relb[4*i+3] = __float2bfloat16(v.w * 8.f);
    }
  } else if (blk < 3584) {
    int idx = (blk - 3328) * 256 + tid;
    int f = idx & 31, s = idx >> 5;
    float inv = powf(10000.f, -(float)f * (1.f/32.f));
    float a = (float)s * inv;
    cost[idx] = cosf(a);
    sint[idx] = sinf(a);
  } else {
    int i = (blk - 3584) * 256 + tid;
    if (i < 3072) bqkv[i] = i < 1024 ? bq[i] : (i < 2048 ? bk[i-1024] : bv[i-2048]);
  }
}

// ---------------- GEMM core ----------------
// MODE 0: fused QKV epilogue (rope for q/k -> [H][S][64]; V -> TRANSPOSED [H][64][S])
// MODE 1: f32 out + bias
template<int BM, int MODE>
__global__ __launch_bounds__(256) void gemm_k(const __hip_bfloat16* __restrict__ A,
                                              const __hip_bfloat16* __restrict__ BT,
                                              const float* __restrict__ bias,
                                              const float* __restrict__ cost,
                                              const float* __restrict__ sint,
                                              __hip_bfloat16* __restrict__ qhh,
                                              __hip_bfloat16* __restrict__ khh,
                                              __hip_bfloat16* __restrict__ vt,
                                              float* __restrict__ outf,
                                              int K) {
  constexpr int MI = BM/32;
  __shared__ __hip_bfloat16 As[2][BM*64];
  __shared__ __hip_bfloat16 Bs[2][128*64];
  int tid = threadIdx.x, lane = tid & 63, w = tid >> 6;
  int rowq = lane & 15, hi = lane >> 4, ksel = hi << 3;
  int wr = (w >> 1) * (BM/2), wc = (w & 1) * 64;
  int m0 = blockIdx.y * BM, n0 = blockIdx.x * 128;
  int l3 = lane >> 3, l7 = lane & 7;
  f32x4 acc[MI][4] = {};

  auto stage = [&](int k0, int buf) {
    const char* Ap = (const char*)A + ((size_t)(m0 + w*(BM/4)) * K + k0) * 2;
    const char* Bp = (const char*)BT + ((size_t)(n0 + w*32) * K + k0) * 2;
    char* Ad = (char*)&As[buf][w*(BM/4)*64];
    char* Bd = (char*)&Bs[buf][w*32*64];
    for (int i = 0; i < MI; ++i)
      GLDS16(Ap + (size_t)(i*8 + l3)*(K*2) + l7*16, Ad + i*1024);
    for (int i = 0; i < 4; ++i)
      GLDS16(Bp + (size_t)(i*8 + l3)*(K*2) + l7*16, Bd + i*1024);
  };

  stage(0, 0);
  __syncthreads();
  int buf = 0;
  int nk = K >> 6;
  for (int t = 0; t < nk; ++t) {
    if (t + 1 < nk) stage((t+1)*64, buf^1);
    for (int kk = 0; kk < 64; kk += 32) {
      bf16x8 a[MI], b[4];
      for (int i = 0; i < MI; ++i) a[i] = *(const bf16x8*)&As[buf][(wr + i*16 + rowq)*64 + kk + ksel];
      for (int j = 0; j < 4; ++j)  b[j] = *(const bf16x8*)&Bs[buf][(wc + j*16 + rowq)*64 + kk + ksel];
      for (int i = 0; i < MI; ++i)
        for (int j = 0; j < 4; ++j)
          acc[i][j] = MFMA16(a[i], b[j], acc[i][j]);
    }
    __syncthreads();
    buf ^= 1;
  }

  if constexpr (MODE == 0) {
    int matsel = n0 >> 10, ncol = n0 & 1023;
    float bcol[4];
    for (int j = 0; j < 4; ++j) bcol[j] = bias[n0 + wc + j*16 + rowq];
    if (matsel < 2) {
      __hip_bfloat16* dst = matsel ? khh : qhh;
      float qs = matsel ? 1.0f : QS;
      for (int i = 0; i < MI; ++i)
        for (int rg = 0; rg < 4; ++rg) {
          int s = m0 + wr + i*16 + hi*4 + rg;
          for (int j = 0; j < 2; ++j) {
            int colp = ncol + wc + j*16 + rowq;
            int hh = colp >> 6, f = colp & 31;
            float c = cost[s*32 + f], sn = sint[s*32 + f];
            float v1 = acc[i][j][rg]   + bcol[j];
            float v2 = acc[i][j+2][rg] + bcol[j+2];
            dst[((size_t)hh*S_ + s)*64 + f]      = __float2bfloat16((v1*c - v2*sn) * qs);
            dst[((size_t)hh*S_ + s)*64 + f + 32] = __float2bfloat16((v2*c + v1*sn) * qs);
          }
        }
    } else {
      for (int i = 0; i < MI; ++i)
        for (int j = 0; j < 4; ++j) {
          int colp = ncol + wc + j*16 + rowq;
          int hh = colp >> 6, d = colp & 63;
          int s0b = m0 + wr + i*16 + hi*4;
          __hip_bfloat16 tmp[4];
          for (int rg = 0; rg < 4; ++rg)
            tmp[rg] = __float2bfloat16(acc[i][j][rg] + bcol[j]);
          *(ushort4*)(vt + ((size_t)hh*64 + d)*S_ + s0b) = *(ushort4*)tmp;
        }
    }
  } else {
    for (int i = 0; i < MI; ++i)
      for (int rg = 0; rg < 4; ++rg) {
        int row = m0 + wr + i*16 + hi*4 + rg;
        for (int j = 0; j < 4; ++j) {
          int col = n0 + wc + j*16 + rowq;
          outf[(size_t)row*E_ + col] = acc[i][j][rg] + bias[col];
        }
      }
  }
}

// ---------------- attention: 4-wave, 2-way split-K, f32 W window, counted-vmcnt barrier ----
__global__ __launch_bounds__(256,2) void attn_k(const __hip_bfloat16* __restrict__ qh,
                                                const __hip_bfloat16* __restrict__ kh,
                                                const __hip_bfloat16* __restrict__ vt,
                                                const __hip_bfloat16* __restrict__ relb,
                                                __hip_bfloat16* __restrict__ opart,
                                                float2* __restrict__ ml) {
  int h = blockIdx.x & 15, p = blockIdx.x >> 4;
  int tid = threadIdx.x, lane = tid & 63, w = tid >> 6;   // w in [0,4)
  int rowq = lane & 15, hi = lane >> 4, ksel = hi << 3;
  int l3 = lane >> 3, l7 = lane & 7;
  int swz = (l7*16) ^ (l3 << 4);
  __shared__ __hip_bfloat16 Ks[2][4096];      // [64][64] linear, XOR-swizzled content
  __shared__ __hip_bfloat16 Vs[2][4096];      // [d][key] linear, XOR-swizzled content
  __shared__ float Wf[4][16*82];              // f32 W window: 16 rows x 328B
  __shared__ char  Psb[4][4096];              // P bf16: 16 rows x 256B, 16B-XOR
  float* wrow = &Wf[w][rowq*82];
  char* pp = Psb[w] + rowq*256;
  int sw8 = (rowq & 7) << 4;
  int pcol0 = ((hi*16)      ^ ((rowq & 7) << 4)) >> 1;
  int pcol1 = ((64 + hi*16) ^ ((rowq & 7) << 4)) >> 1;
  int c0 = hi*4 + 15 - rowq;

  for (int ph = 0; ph < 2; ++ph) {
    int qb = ph ? 31 - p : p;
    int T = qb + 1;
    int t0 = ph ? (T + 1) >> 1 : 0;
    int t1 = ph ? T : (T + 1) >> 1;
    int i0w = qb*64 + w*16;

    const __hip_bfloat16* qrow = qh + ((size_t)h*S_ + i0w + rowq)*64 + ksel;
    bf16x8 q0 = *(const bf16x8*)(qrow);
    bf16x8 q1 = *(const bf16x8*)(qrow + 32);
    f32x4 o[4] = {};
    float m = -1e30f, l = 0.f;

    auto stage = [&](int t, int buf) {
      int j0 = t * 64;
      const char* kp = (const char*)(kh + ((size_t)h*S_ + j0 + w*16)*64);
      const char* vp = (const char*)(vt + ((size_t)(h*64 + w*16))*S_ + j0);
      char* kd = (char*)&Ks[buf][w*16*64];
      char* vd = (char*)&Vs[buf][w*16*64];
      for (int i = 0; i < 2; ++i) {
        GLDS16(kp + (size_t)(i*8 + l3)*128  + swz, kd + i*1024);
        GLDS16(vp + (size_t)(i*8 + l3)*4096 + swz, vd + i*1024);
      }
    };
    auto ldrel = [&](int t, bf16x8* rr) {
      const __hip_bfloat16* rp = relb + (size_t)(t*64 - i0w + 2032 + rowq)*64 + ksel;
      #pragma unroll
      for (int nf = 0; nf < 5; ++nf) {
        rr[nf*2]   = *(const bf16x8*)(rp + nf*1024);
        rr[nf*2+1] = *(const bf16x8*)(rp + nf*1024 + 32);
      }
    };

    if (t0 < t1) {
      bf16x8 rc[10];
      ldrel(t0, rc);
      stage(t0, 0);
      __syncthreads();
      int buf = 0;
      for (int t = t0; t < t1; ++t) {
        bool more = (t + 1 < t1);
        if (more) stage(t+1, buf^1);

        f32x4 sa[4] = {};
        f32x4 wt[5] = {};
        __builtin_amdgcn_s_setprio(1);
        for (int kk = 0; kk < 2; ++kk) {
          bf16x8 qf = kk ? q1 : q0;
          int pc = kk ? pcol1 : pcol0;
          for (int nf = 0; nf < 4; ++nf) {
            bf16x8 kf = *(const bf16x8*)&Ks[buf][(nf*16 + rowq)*64 + pc];
            sa[nf] = MFMA16(kf, qf, sa[nf]);          // D[key][q]
          }
          for (int nf = 0; nf < 5; ++nf)
            wt[nf] = MFMA16(rc[nf*2+kk], qf, wt[nf]); // D[relrow][q]
        }
        __builtin_amdgcn_s_setprio(0);

        // store W window (f32, un-swizzled 328B-stride rows -> ~4-way max)
        #pragma unroll
        for (int nf = 0; nf < 5; ++nf) {
          *(float2*)(wrow + nf*16 + hi*4)     = make_float2(wt[nf][0], wt[nf][1]);
          *(float2*)(wrow + nf*16 + hi*4 + 2) = make_float2(wt[nf][2], wt[nf][3]);
        }

        // single-buffer rel prefetch: rc's MFMA readers are done, reload in place
        if (more) ldrel(t+1, rc);

        // gather bias + softmax (lane-local, q=rowq); mask only the diagonal tile
        float sv[4][4];
        #pragma unroll
        for (int rg = 0; rg < 4; ++rg) {
          int cc = c0 + rg;
          #pragma unroll
          for (int nf = 0; nf < 4; ++nf)
            sv[nf][rg] = sa[nf][rg] + wrow[nf*16 + cc];
        }
        float tm = -1e30f;
        bool diag = (t == qb);
        int lim = w*16 + rowq;
        #pragma unroll
        for (int nf = 0; nf < 4; ++nf)
          #pragma unroll
          for (int rg = 0; rg < 4; ++rg) {
            int kl = nf*16 + hi*4 + rg;
            if (diag && kl > lim) sv[nf][rg] = -1e30f;
            tm = fmaxf(tm, sv[nf][rg]);
          }
        tm = fmaxf(tm, __shfl_xor(tm, 16));
        tm = fmaxf(tm, __shfl_xor(tm, 32));

        // defer-max: skip rescale when tile max is within 8 of running max (wave-uniform)
        bool defer = __all(tm <= m + 8.0f);
        float al = 1.0f;
        if (!defer) {
          float mnew = fmaxf(m, tm);
          al = exp2f(m - mnew);
          m = mnew;
        }
        float ls = 0.f;
        float pe[4][4];
        #pragma unroll
        for (int nf = 0; nf < 4; ++nf)
          #pragma unroll
          for (int rg = 0; rg < 4; ++rg) {
            float e = exp2f(sv[nf][rg] - m);
            pe[nf][rg] = e;
            ls += e;
          }
        l = l * al + ls;
        #pragma unroll
        for (int nf = 0; nf < 4; ++nf) {
          uint2 u = { pk2(pe[nf][0], pe[nf][1]), pk2(pe[nf][2], pe[nf][3]) };
          *(uint2*)(pp + ((nf*32 + hi*8) ^ sw8)) = u;
        }
        if (!defer) {
          float alq[4];
          #pragma unroll
          for (int rg = 0; rg < 4; ++rg) alq[rg] = __shfl(al, hi*4 + rg, 16);
          #pragma unroll
          for (int df = 0; df < 4; ++df)
            #pragma unroll
            for (int rg = 0; rg < 4; ++rg) o[df][rg] *= alq[rg];
        }

        // PV
        __builtin_amdgcn_s_setprio(1);
        for (int kk = 0; kk < 2; ++kk) {
          bf16x8 a = *(const bf16x8*)(pp + ((kk*64 + hi*16) ^ sw8));
          int pc = kk ? pcol1 : pcol0;
          for (int df = 0; df < 4; ++df) {
            bf16x8 b = *(const bf16x8*)&Vs[buf][(df*16 + rowq)*64 + pc];
            o[df] = MFMA16(a, b, o[df]);
          }
        }
        __builtin_amdgcn_s_setprio(0);

        // counted-vmcnt barrier (T4-lite)
        __builtin_amdgcn_sched_barrier(0);
        asm volatile("s_waitcnt vmcnt(10)" ::: "memory");
        __builtin_amdgcn_s_barrier();
        __builtin_amdgcn_sched_barrier(0);
        buf ^= 1;
      }
    }

    // phase epilogue: partial o (unnormalized), m, l for slot ph
    float lt = l;
    lt += __shfl_xor(lt, 16);
    lt += __shfl_xor(lt, 32);
    if (lane < 16) ml[((size_t)ph*S_ + i0w + rowq)*H_ + h] = make_float2(m, lt);
    #pragma unroll
    for (int df = 0; df < 4; ++df)
      #pragma unroll
      for (int rg = 0; rg < 4; ++rg)
        opart[(size_t)ph*S_*E_ + (size_t)(i0w + hi*4 + rg)*E_ + h*64 + df*16 + rowq] =
            __float2bfloat16(o[df][rg]);
    __syncthreads();
  }
}

// ---------------- combine 2 split-K partials -> aout bf16 ----------------
__global__ __launch_bounds__(256) void combine_k(const __hip_bfloat16* __restrict__ opart,
                                                 const float2* __restrict__ ml,
                                                 __hip_bfloat16* __restrict__ aout) {
  int r = blockIdx.x, tid = threadIdx.x;
  int c = tid * 4, h = c >> 6;
  float2 a0 = ml[(size_t)r*H_ + h];
  float2 a1 = ml[((size_t)S_ + r)*H_ + h];
  float M = fmaxf(a0.x, a1.x);
  float w0 = exp2f(a0.x - M), w1 = exp2f(a1.x - M);
  float dinv = 1.0f / (w0*a0.y + w1*a1.y);
  w0 *= dinv; w1 *= dinv;
  const unsigned short* o0 = (const unsigned short*)opart + (size_t)r*E_ + c;
  const unsigned short* o1 = o0 + (size_t)S_*E_;
  ushort4 u0 = *(const ushort4*)o0;
  ushort4 u1 = *(const ushort4*)o1;
  __hip_bfloat16 res[4];
  res[0] = __float2bfloat16(w0*ubf(u0.x) + w1*ubf(u1.x));
  res[1] = __float2bfloat16(w0*ubf(u0.y) + w1*ubf(u1.y));
  res[2] = __float2bfloat16(w0*ubf(u0.z) + w1*ubf(u1.z));
  res[3] = __float2bfloat16(w0*ubf(u0.w) + w1*ubf(u1.w));
  *(ushort4*)((unsigned short*)aout + (size_t)r*E_ + c) = *(ushort4*)res;
}

// ---------------- launcher ----------------
extern "C" void kernel_launch(void* const* d_in, const int* in_sizes, int n_in,
                              void* d_out, int out_size, void* d_ws, size_t ws_size,
                              hipStream_t stream) {
  const float* x   = (const float*)d_in[0];
  const float* Wq  = (const float*)d_in[2];
  const float* bq  = (const float*)d_in[3];
  const float* Wk  = (const float*)d_in[4];
  const float* bk  = (const float*)d_in[5];
  const float* Wv  = (const float*)d_in[6];
  const float* bv  = (const float*)d_in[7];
  const float* Wo  = (const float*)d_in[8];
  const float* bo  = (const float*)d_in[9];
  const float* rel = (const float*)d_in[10];
  float* out = (float*)d_out;

  char* ws = (char*)d_ws;
  size_t off = 0;
  auto alloc = [&](size_t bytes) -> void* {
    void* p = ws + off;
    off = (off + bytes + 255) & ~(size_t)255;
    return p;
  };
  // ---- region dead during attn (aliased by opart, 8 MB) ----
  __hip_bfloat16* xb    = (__hip_bfloat16*)alloc((size_t)S_*E_*2);       // 4 MB
  __hip_bfloat16* wqkvT = (__hip_bfloat16*)alloc((size_t)3*E_*E_*2);     // 6 MB
  float* cost = (float*)alloc((size_t)S_*32*4);
  float* sint = (float*)alloc((size_t)S_*32*4);
  float* bqkv = (float*)alloc((size_t)3072*4);
  if (off < (size_t)16*1024*1024) off = (size_t)16*1024*1024;
  // ---- live during attn ----
  __hip_bfloat16* woT   = (__hip_bfloat16*)alloc((size_t)E_*E_*2);
  __hip_bfloat16* relb  = (__hip_bfloat16*)alloc((size_t)4095*64*2);
  __hip_bfloat16* qhh  = (__hip_bfloat16*)alloc((size_t)S_*E_*2);
  __hip_bfloat16* khh  = (__hip_bfloat16*)alloc((size_t)S_*E_*2);
  __hip_bfloat16* vth  = (__hip_bfloat16*)alloc((size_t)S_*E_*2);
  __hip_bfloat16* aout = (__hip_bfloat16*)alloc((size_t)S_*E_*2);
  float2* ml = (float2*)alloc((size_t)2*S_*H_*8);

  __hip_bfloat16* opart = (__hip_bfloat16*)ws;   // 8 MB over the attn-dead prefix

  prep_k<<<3596, 256, 0, stream>>>(x, rel, Wq, Wk, Wv, Wo, bq, bk, bv,
                                   xb, relb, wqkvT, woT, bqkv, cost, sint);

  // fused QKV projection + rope + V-transpose (BM=64: 768 blocks = 3/CU exact)
  gemm_k<64,0><<<dim3(24,32), 256, 0, stream>>>(xb, wqkvT, bqkv, cost, sint,
                                                qhh, khh, vth, nullptr, E_);

  attn_k<<<512, 256, 0, stream>>>(qhh, khh, vth, relb, opart, ml);
  combine_k<<<S_, 256, 0, stream>>>(opart, ml, aout);

  // out-projection: BM=32 -> 512 blocks = 2/CU
  gemm_k<32,1><<<dim3(8,64), 256, 0, stream>>>(aout, woT, bo, nullptr, nullptr,
                                               nullptr, nullptr, nullptr, out, E_);
}